// Round 11
// baseline (274.369 us; speedup 1.0000x reference)
//
#include <hip/hip_runtime.h>
#include <stdint.h>

typedef unsigned short u16;
typedef __bf16 bf16x8 __attribute__((ext_vector_type(8)));
typedef float f32x4 __attribute__((ext_vector_type(4)));

#define KDIM   768
#define MP     6400      // padded token-row count (50 * 128)
#define MREAL  6304      // 32 * 197
#define SLOT   ((size_t)MP * KDIM)
#define WSZ    ((size_t)KDIM * KDIM)
#define QSCALE_L 0.18033688011112042f   // 0.125 * log2(e): QK^T lands in log2 domain
#define BIGL     1.4426950e9f           // 1e9 * log2(e)

struct Ptr9 { const float* p[9]; };
struct Ptr7 { const float* p[7]; };

__device__ __forceinline__ u16 f2b(float f) {
  uint32_t x = __float_as_uint(f);
  x += 0x7FFFu + ((x >> 16) & 1u);   // RNE
  return (u16)(x >> 16);
}

__device__ __forceinline__ float b2f(u16 v) {
  return __uint_as_float(((uint32_t)v) << 16);
}

__device__ __forceinline__ void async16(const void* g, void* l) {
  __builtin_amdgcn_global_load_lds(
      (__attribute__((address_space(1))) void*)(uintptr_t)g,
      (__attribute__((address_space(3))) void*)l, 16, 0, 0);
}

// ---------------- fp32 -> bf16 conversion (x + 8 weight matrices) -------------
__global__ __launch_bounds__(256) void k_convert(Ptr9 src, u16* __restrict__ xb,
                                                 u16* __restrict__ wall) {
  const int XN4 = MREAL * KDIM / 4;
  const int WN4 = (int)(WSZ / 4);
  const int total = XN4 + 8 * WN4;
  for (int i = blockIdx.x * blockDim.x + threadIdx.x; i < total;
       i += gridDim.x * blockDim.x) {
    const float4* sp; ushort4* dp; int off;
    if (i < XN4) { sp = (const float4*)src.p[0]; dp = (ushort4*)xb; off = i; }
    else {
      int t = i - XN4; int slot = t / WN4; off = t - slot * WN4;
      sp = (const float4*)src.p[1 + slot];
      dp = (ushort4*)(wall + (size_t)slot * WSZ);
    }
    float4 v = sp[off];
    ushort4 u;
    u.x = f2b(v.x); u.y = f2b(v.y); u.z = f2b(v.z); u.w = f2b(v.w);
    dp[off] = u;
  }
}

// ---------------- bf16 MFMA GEMM: C = A @ W^T + bias -------------------------
__global__ __launch_bounds__(256) void k_gemm(const u16* __restrict__ A,
                                              const u16* __restrict__ W,
                                              Ptr7 bias,
                                              u16* __restrict__ outb,
                                              float* __restrict__ outf,
                                              float scale0, int guard) {
  __shared__ u16 As[128 * 32];
  __shared__ u16 Bs[128 * 32];
  const int tid = threadIdx.x;
  const int w = tid >> 6, lane = tid & 63;
  const int li = lane & 15, g = lane >> 4;
  const int brow = blockIdx.x, bcol = blockIdx.y, z = blockIdx.z;
  const u16* Wz = W + (size_t)z * WSZ;
  const float* bz = bias.p[z];
  const int wr = (w >> 1) * 64, wc = (w & 1) * 64;
  f32x4 acc[4][4] = {};

  for (int k0 = 0; k0 < KDIM; k0 += 32) {
    __syncthreads();
#pragma unroll
    for (int c = 0; c < 2; ++c) {
      int cbase = (c * 4 + w) * 64;
      int chunk = cbase + lane;
      int row = chunk >> 2, kg = chunk & 3;
      async16(A  + (size_t)(brow * 128 + row) * KDIM + k0 + kg * 8,
              (char*)As + cbase * 16);
      async16(Wz + (size_t)(bcol * 128 + row) * KDIM + k0 + kg * 8,
              (char*)Bs + cbase * 16);
    }
    asm volatile("s_waitcnt vmcnt(0)" ::: "memory");
    __syncthreads();

    bf16x8 af[4], bfr[4];
#pragma unroll
    for (int i = 0; i < 4; ++i) {
      af[i]  = *(const bf16x8*)(As + (wr + i * 16 + li) * 32 + g * 8);
      bfr[i] = *(const bf16x8*)(Bs + (wc + i * 16 + li) * 32 + g * 8);
    }
#pragma unroll
    for (int i = 0; i < 4; ++i)
#pragma unroll
      for (int j = 0; j < 4; ++j)
        acc[i][j] = __builtin_amdgcn_mfma_f32_16x16x32_bf16(af[i], bfr[j],
                                                            acc[i][j], 0, 0, 0);
  }

  const float scz = (z == 0) ? scale0 : 1.0f;
  if (outf == nullptr) {
    u16* O = outb + (size_t)z * SLOT;
#pragma unroll
    for (int j = 0; j < 4; ++j) {
      int col = bcol * 128 + wc + j * 16 + li;
      float bsv = bz[col];
#pragma unroll
      for (int i = 0; i < 4; ++i) {
        int row = brow * 128 + wr + i * 16 + g * 4;
#pragma unroll
        for (int r = 0; r < 4; ++r)
          O[(size_t)(row + r) * KDIM + col] = f2b((acc[i][j][r] + bsv) * scz);
      }
    }
  } else {
#pragma unroll
    for (int j = 0; j < 4; ++j) {
      int col = bcol * 128 + wc + j * 16 + li;
      float bsv = bz[col];
#pragma unroll
      for (int i = 0; i < 4; ++i) {
        int row = brow * 128 + wr + i * 16 + g * 4;
#pragma unroll
        for (int r = 0; r < 4; ++r)
          if (row + r < guard)
            outf[(size_t)(row + r) * KDIM + col] = acc[i][j][r] + bsv;
      }
    }
  }
}

// ---------------- fused 5-mask attention -------------------------------------
// Grid (2,12,32); block = 8 waves (512 thr), wave w owns rt = bx*8+w (<=12).
// BARRIER-FREE mask loop: K fragments are read directly from global (each
// (b,h) K tile is 25 KB and every wave reads all of it -> L1-resident after
// first touch; line-coalesced 16 rows x 128B per tile). Only ONE
// __syncthreads (after VT staging); waves free-run and naturally desync so
// MFMA/VALU/mem phases of the 4 waves/SIMD overlap (this was the R5-R9
// bottleneck: barrier-locked phase lockstep).
// V^T in LDS, pi-permuted along j (j=t*16+g*4+r <-> k=(t>>1)*32+g*8+(t&1)*4+r)
// so each lane's PV A-fragment is its OWN softmax regs. 480B row stride:
// 16B-aligned b128 reads, provably even 8-lanes-per-16B-slot distribution.
// launch_bounds(512,2) -> 128 VGPR cap, no spill (R9-verified live set).
// Softmax numerics = R3/R5/R9 proven core.
__global__ __launch_bounds__(512, 2) void k_attn(const u16* __restrict__ qkv,
                                                 u16* __restrict__ att) {
  __shared__ __align__(16) u16 VT[64 * 240];   // 30.7 KB; cols [0,224) used
  char* VTc = (char*)VT;
  const int tid = threadIdx.x;
  const int w = tid >> 6, lane = tid & 63;
  const int li = lane & 15, g = lane >> 4;
  const int bx = blockIdx.x, h = blockIdx.y, b = blockIdx.z;
  const int rt = bx * 8 + w;
  const size_t rowbase = (size_t)b * 197;
  const int cb = h * 64;
  const u16* Q = qkv;
  const u16* V = qkv + 6 * SLOT;
  const bool task = (rt <= 12);

  // --- V^T staging, pi-order: VT[d][k(j)] = V[j][d]; j-pairs -> b32 writes ---
  for (int e = tid; e < 112 * 8; e += 512) {
    int jp = e >> 3, d8 = e & 7;
    int j0 = jp * 2;
    uint4 v0 = make_uint4(0, 0, 0, 0), v1 = make_uint4(0, 0, 0, 0);
    if (j0 < 197)     v0 = *(const uint4*)(V + (rowbase + j0) * KDIM + cb + d8 * 8);
    if (j0 + 1 < 197) v1 = *(const uint4*)(V + (rowbase + j0 + 1) * KDIM + cb + d8 * 8);
    int t = j0 >> 4;
    int k0 = (t >> 1) * 32 + ((j0 >> 2) & 3) * 8 + (t & 1) * 4 + (j0 & 3);
    uint32_t w0[4] = {v0.x, v0.y, v0.z, v0.w};
    uint32_t w1[4] = {v1.x, v1.y, v1.z, v1.w};
#pragma unroll
    for (int q = 0; q < 8; ++q) {
      int d = d8 * 8 + q;
      uint32_t a  = (q & 1) ? (w0[q >> 1] >> 16) : (w0[q >> 1] & 0xffffu);
      uint32_t bb = (q & 1) ? (w1[q >> 1] >> 16) : (w1[q >> 1] & 0xffffu);
      *(uint32_t*)(VTc + d * 480 + k0 * 2) = a | (bb << 16);
    }
  }

  // per-lane i-side mask state
  const int i_ = rt * 16 + li;
  const int pi = i_ - 1;
  const int ri = pi / 14, ci = pi % 14;
  const bool i0 = (i_ == 0);

  // running j-side seed at (t=0, r=0): pj = g*4 - 1
  const int rs_init = (g * 4 - 1) / 14;
  const int cs_init = (g * 4 - 1) % 14;        // -1, 3, 7, 11

  bf16x8 qa0, qa1;
  {
    const size_t qrow = rowbase + (size_t)rt * 16 + li;   // < MP rows, finite
    qa0 = *(const bf16x8*)(Q + qrow * KDIM + cb + g * 8);
    qa1 = *(const bf16x8*)(Q + qrow * KDIM + cb + 32 + g * 8);
  }

  __syncthreads();                   // VT ready; the ONLY block-wide barrier

  f32x4 oacc[4] = {};
  const int nmask = (rt == 0) ? 5 : 4;

  if (task) {
    for (int m = 0; m < nmask; ++m) {
      // QK^T, K direct from global (L1-resident after first wave touches it).
      // Swapped operands: lane holds S^T[j][i=li].
      f32x4 s[13];
      __builtin_amdgcn_s_setprio(1);
#pragma unroll
      for (int t = 0; t < 13; ++t) {
        const u16* Kr = qkv + (size_t)(1 + m) * SLOT +
                        (rowbase + t * 16 + li) * KDIM + cb;
        bf16x8 kb0 = *(const bf16x8*)(Kr + g * 8);
        bf16x8 kb1 = *(const bf16x8*)(Kr + 32 + g * 8);
        f32x4 zz = {};
        zz = __builtin_amdgcn_mfma_f32_16x16x32_bf16(kb0, qa0, zz, 0, 0, 0);
        zz = __builtin_amdgcn_mfma_f32_16x16x32_bf16(kb1, qa1, zz, 0, 0, 0);
        s[t] = zz;
      }
      __builtin_amdgcn_s_setprio(0);

      // analytic mask (log2 domain, R3 numerics) + post-mask lane-local max
      float mx = -3.0e38f;
      int cs = cs_init, rs = rs_init;
#pragma unroll
      for (int t = 0; t < 13; ++t) {
        int jv = t * 16 + g * 4;
        int cjr = cs, rjr = rs;
#pragma unroll
        for (int r = 0; r < 4; ++r) {
          bool mk;
          if (m == 0)      mk = ci < cjr;    // left
          else if (m == 1) mk = ci > cjr;    // right
          else if (m == 2) mk = ri < rjr;    // up
          else if (m == 3) mk = ri > rjr;    // down
          else             mk = (i_ == jv);  // ident (rt==0 wave only)
          if (i0 | (jv == 0)) mk = false;    // CLS row/col: uniform -BIG shift
          float sv = s[t][r] - (mk ? 0.f : BIGL);
          if (jv >= 197) sv = -3.0e38f;      // pad cols: hard kill (NaN-safe)
          s[t][r] = sv;
          mx = fmaxf(mx, sv);
          ++jv; ++cjr; if (cjr == 14) { cjr = 0; ++rjr; }
        }
        cs += 2; ++rs; if (cs >= 14) { cs -= 14; ++rs; }   // seed advance (+16)
      }
      mx = fmaxf(mx, __shfl_xor(mx, 16));
      mx = fmaxf(mx, __shfl_xor(mx, 32));
      float sum = 0.f;
#pragma unroll
      for (int t = 0; t < 13; ++t)
#pragma unroll
        for (int r = 0; r < 4; ++r) {
          float e_ = exp2f(s[t][r] - mx);
          s[t][r] = e_;
          sum += e_;
        }
      sum += __shfl_xor(sum, 16);
      sum += __shfl_xor(sum, 32);
      const float inv = 1.0f / sum;

      // early full pack: s (52 f32) -> pk (7 bf16x8); s dies here
      union PU { uint32_t u[4]; bf16x8 v; };
      PU pk[7];
#pragma unroll
      for (int kt = 0; kt < 7; ++kt) {
        {
          float a0 = s[2 * kt][0] * inv, a1 = s[2 * kt][1] * inv;
          float a2 = s[2 * kt][2] * inv, a3 = s[2 * kt][3] * inv;
          asm("v_cvt_pk_bf16_f32 %0, %1, %2" : "=v"(pk[kt].u[0]) : "v"(a0), "v"(a1));
          asm("v_cvt_pk_bf16_f32 %0, %1, %2" : "=v"(pk[kt].u[1]) : "v"(a2), "v"(a3));
        }
        if (kt < 6) {
          float b0 = s[2 * kt + 1][0] * inv, b1 = s[2 * kt + 1][1] * inv;
          float b2 = s[2 * kt + 1][2] * inv, b3 = s[2 * kt + 1][3] * inv;
          asm("v_cvt_pk_bf16_f32 %0, %1, %2" : "=v"(pk[kt].u[2]) : "v"(b0), "v"(b1));
          asm("v_cvt_pk_bf16_f32 %0, %1, %2" : "=v"(pk[kt].u[3]) : "v"(b2), "v"(b3));
        } else { pk[kt].u[2] = 0; pk[kt].u[3] = 0; }
      }

      // PV: register A-fragments + aligned b128 VT reads
      __builtin_amdgcn_s_setprio(1);
#pragma unroll
      for (int kt = 0; kt < 7; ++kt) {
#pragma unroll
        for (int dt = 0; dt < 4; ++dt) {
          int row = dt * 16 + li;
          bf16x8 vb = *(const bf16x8*)(VTc + row * 480 + kt * 64 + g * 16);
          oacc[dt] = __builtin_amdgcn_mfma_f32_16x16x32_bf16(pk[kt].v, vb,
                                                             oacc[dt], 0, 0, 0);
        }
      }
      __builtin_amdgcn_s_setprio(0);
    }

    // identity-mask contribution for non-CLS rows: one-hot P -> +V[i]
    if (rt > 0) {
#pragma unroll
      for (int dt = 0; dt < 4; ++dt)
#pragma unroll
        for (int r = 0; r < 4; ++r) {
          int i2 = rt * 16 + g * 4 + r;        // 16..207; k slots >=197 zeroed
          int t2 = i2 >> 4;
          int k2 = (t2 >> 1) * 32 + ((i2 >> 2) & 3) * 8 + (t2 & 1) * 4 + (i2 & 3);
          int row = dt * 16 + li;
          u16 hv = *(const u16*)(VTc + row * 480 + k2 * 2);
          oacc[dt][r] += b2f(hv);
        }
    }

#pragma unroll
    for (int dt = 0; dt < 4; ++dt)
#pragma unroll
      for (int r = 0; r < 4; ++r) {
        int i2 = rt * 16 + g * 4 + r;
        if (i2 < 197)
          att[(rowbase + i2) * KDIM + cb + dt * 16 + li] = f2b(oacc[dt][r]);
      }
  }
}

// -----------------------------------------------------------------------------
extern "C" void kernel_launch(void* const* d_in, const int* in_sizes, int n_in,
                              void* d_out, int out_size, void* d_ws, size_t ws_size,
                              hipStream_t stream) {
  (void)in_sizes; (void)n_in; (void)out_size; (void)ws_size;
  const float* x      = (const float*)d_in[0];
  const float* q_w    = (const float*)d_in[1];
  const float* q_b    = (const float*)d_in[2];
  const float* kA_w   = (const float*)d_in[3];
  const float* kA_b   = (const float*)d_in[4];
  const float* kB_w   = (const float*)d_in[5];
  const float* kB_b   = (const float*)d_in[6];
  const float* kC_w   = (const float*)d_in[7];
  const float* kC_b   = (const float*)d_in[8];
  const float* kD_w   = (const float*)d_in[9];
  const float* kD_b   = (const float*)d_in[10];
  const float* kE_w   = (const float*)d_in[11];
  const float* kE_b   = (const float*)d_in[12];
  const float* v_w    = (const float*)d_in[13];
  const float* v_b    = (const float*)d_in[14];
  const float* proj_w = (const float*)d_in[15];
  const float* proj_b = (const float*)d_in[16];
  float* out = (float*)d_out;

  u16* xb   = (u16*)d_ws;                 // SLOT
  u16* qkv  = xb + SLOT;                  // 7 * SLOT
  u16* wall = qkv + 7 * SLOT;             // 8 * WSZ
  u16* att  = xb;                         // reuse after gemm1 consumed x_b

  Ptr9 cs;
  cs.p[0] = x;    cs.p[1] = q_w;  cs.p[2] = kA_w; cs.p[3] = kB_w;
  cs.p[4] = kC_w; cs.p[5] = kD_w; cs.p[6] = kE_w; cs.p[7] = v_w;
  cs.p[8] = proj_w;
  k_convert<<<dim3(2048), dim3(256), 0, stream>>>(cs, xb, wall);

  Ptr7 b1;
  b1.p[0] = q_b;  b1.p[1] = kA_b; b1.p[2] = kB_b; b1.p[3] = kC_b;
  b1.p[4] = kD_b; b1.p[5] = kE_b; b1.p[6] = v_b;
  k_gemm<<<dim3(50, 6, 7), dim3(256), 0, stream>>>(xb, wall, b1, qkv, nullptr,
                                                   QSCALE_L, 0);

  k_attn<<<dim3(2, 12, 32), dim3(512), 0, stream>>>(qkv, att);

  Ptr7 b2;
  for (int i = 0; i < 7; ++i) b2.p[i] = proj_b;
  k_gemm<<<dim3(50, 6, 1), dim3(256), 0, stream>>>(att, wall + 7 * WSZ, b2,
                                                   nullptr, out, 1.0f, MREAL);
}

// Round 13
// 199.583 us; speedup vs baseline: 1.3747x; 1.3747x over previous
//
#include <hip/hip_runtime.h>
#include <stdint.h>

typedef unsigned short u16;
typedef __bf16 bf16x8 __attribute__((ext_vector_type(8)));
typedef float f32x4 __attribute__((ext_vector_type(4)));

#define KDIM   768
#define MP     6400      // padded token-row count (50 * 128)
#define MREAL  6304      // 32 * 197
#define SLOT   ((size_t)MP * KDIM)
#define WSZ    ((size_t)KDIM * KDIM)
#define QSCALE_L 0.18033688011112042f   // 0.125 * log2(e): QK^T lands in log2 domain
#define BIGL     1.4426950e9f           // 1e9 * log2(e)

struct Ptr9 { const float* p[9]; };
struct Ptr7 { const float* p[7]; };

__device__ __forceinline__ u16 f2b(float f) {
  uint32_t x = __float_as_uint(f);
  x += 0x7FFFu + ((x >> 16) & 1u);   // RNE
  return (u16)(x >> 16);
}

__device__ __forceinline__ float b2f(u16 v) {
  return __uint_as_float(((uint32_t)v) << 16);
}

__device__ __forceinline__ void async16(const void* g, void* l) {
  __builtin_amdgcn_global_load_lds(
      (__attribute__((address_space(1))) void*)(uintptr_t)g,
      (__attribute__((address_space(3))) void*)l, 16, 0, 0);
}

// ---------------- fp32 -> bf16 conversion (x + 8 weight matrices) -------------
__global__ __launch_bounds__(256) void k_convert(Ptr9 src, u16* __restrict__ xb,
                                                 u16* __restrict__ wall) {
  const int XN4 = MREAL * KDIM / 4;
  const int WN4 = (int)(WSZ / 4);
  const int total = XN4 + 8 * WN4;
  for (int i = blockIdx.x * blockDim.x + threadIdx.x; i < total;
       i += gridDim.x * blockDim.x) {
    const float4* sp; ushort4* dp; int off;
    if (i < XN4) { sp = (const float4*)src.p[0]; dp = (ushort4*)xb; off = i; }
    else {
      int t = i - XN4; int slot = t / WN4; off = t - slot * WN4;
      sp = (const float4*)src.p[1 + slot];
      dp = (ushort4*)(wall + (size_t)slot * WSZ);
    }
    float4 v = sp[off];
    ushort4 u;
    u.x = f2b(v.x); u.y = f2b(v.y); u.z = f2b(v.z); u.w = f2b(v.w);
    dp[off] = u;
  }
}

// ---------------- bf16 MFMA GEMM: C = A @ W^T + bias -------------------------
__global__ __launch_bounds__(256) void k_gemm(const u16* __restrict__ A,
                                              const u16* __restrict__ W,
                                              Ptr7 bias,
                                              u16* __restrict__ outb,
                                              float* __restrict__ outf,
                                              float scale0, int guard) {
  __shared__ u16 As[128 * 32];
  __shared__ u16 Bs[128 * 32];
  const int tid = threadIdx.x;
  const int w = tid >> 6, lane = tid & 63;
  const int li = lane & 15, g = lane >> 4;
  const int brow = blockIdx.x, bcol = blockIdx.y, z = blockIdx.z;
  const u16* Wz = W + (size_t)z * WSZ;
  const float* bz = bias.p[z];
  const int wr = (w >> 1) * 64, wc = (w & 1) * 64;
  f32x4 acc[4][4] = {};

  for (int k0 = 0; k0 < KDIM; k0 += 32) {
    __syncthreads();
#pragma unroll
    for (int c = 0; c < 2; ++c) {
      int cbase = (c * 4 + w) * 64;
      int chunk = cbase + lane;
      int row = chunk >> 2, kg = chunk & 3;
      async16(A  + (size_t)(brow * 128 + row) * KDIM + k0 + kg * 8,
              (char*)As + cbase * 16);
      async16(Wz + (size_t)(bcol * 128 + row) * KDIM + k0 + kg * 8,
              (char*)Bs + cbase * 16);
    }
    asm volatile("s_waitcnt vmcnt(0)" ::: "memory");
    __syncthreads();

    bf16x8 af[4], bfr[4];
#pragma unroll
    for (int i = 0; i < 4; ++i) {
      af[i]  = *(const bf16x8*)(As + (wr + i * 16 + li) * 32 + g * 8);
      bfr[i] = *(const bf16x8*)(Bs + (wc + i * 16 + li) * 32 + g * 8);
    }
#pragma unroll
    for (int i = 0; i < 4; ++i)
#pragma unroll
      for (int j = 0; j < 4; ++j)
        acc[i][j] = __builtin_amdgcn_mfma_f32_16x16x32_bf16(af[i], bfr[j],
                                                            acc[i][j], 0, 0, 0);
  }

  const float scz = (z == 0) ? scale0 : 1.0f;
  if (outf == nullptr) {
    u16* O = outb + (size_t)z * SLOT;
#pragma unroll
    for (int j = 0; j < 4; ++j) {
      int col = bcol * 128 + wc + j * 16 + li;
      float bsv = bz[col];
#pragma unroll
      for (int i = 0; i < 4; ++i) {
        int row = brow * 128 + wr + i * 16 + g * 4;
#pragma unroll
        for (int r = 0; r < 4; ++r)
          O[(size_t)(row + r) * KDIM + col] = f2b((acc[i][j][r] + bsv) * scz);
      }
    }
  } else {
#pragma unroll
    for (int j = 0; j < 4; ++j) {
      int col = bcol * 128 + wc + j * 16 + li;
      float bsv = bz[col];
#pragma unroll
      for (int i = 0; i < 4; ++i) {
        int row = brow * 128 + wr + i * 16 + g * 4;
#pragma unroll
        for (int r = 0; r < 4; ++r)
          if (row + r < guard)
            outf[(size_t)(row + r) * KDIM + col] = acc[i][j][r] + bsv;
      }
    }
  }
}

// ---------------- fused 5-mask attention -------------------------------------
// R5 champion (174 us) with ONE change: the per-mask analytic mask walk
// (cmp/cndmask/seed chains, run 4.08x per wave) is replaced by keep-bits
// precomputed ONCE per lane (10 u32). The softmax arithmetic pipeline is
// BIT-IDENTICAL to R5: sv = s - (keep ? 0 : BIGL); pads hard-killed to -3e38
// pre-max; post-mask max (shfl-reduced); exp2; serial sum; 1/sum.
// NO allm special-casing: fully-masked rows have all-zero bits -> uniform
// -BIGL -> max shift makes it plain softmax over real j (R5's exact mechanism;
// R4/R12's allm rewrite failed twice with identical absmax - do not revisit).
// Everything else (KL staging+prefetch, P-LDS lag-1 PV, (512,4), grid) = R5.
__global__ __launch_bounds__(512, 4) void k_attn(const u16* __restrict__ qkv,
                                                 u16* __restrict__ att) {
  __shared__ u16 KL[208 * 64];      // 26.0 KB; chunk c holds global chunk c^(row&7)
  __shared__ u16 VT[64][228];       // 28.5 KB; V^T, cols 197..227 zeroed
  __shared__ u16 P[2][8][16][36];   // 18.0 KB; lag-1 rotated per-wave P chunk
  const int tid = threadIdx.x;
  const int w = tid >> 6, lane = tid & 63;
  const int li = lane & 15, g = lane >> 4;
  const int bx = blockIdx.x, h = blockIdx.y, b = blockIdx.z;
  const int rt = bx * 8 + w;
  const size_t rowbase = (size_t)b * 197;
  const int cb = h * 64;
  const u16* Q = qkv;
  const u16* V = qkv + 6 * SLOT;
  const bool task = (rt <= 12);
  const int nmask = (bx == 0) ? 5 : 4;

  // --- K staging: 1664 16B-chunks; wave w covers bases (i*8+w)*64 ------------
  auto stageK = [&](int m) {
    const u16* Kg = qkv + (size_t)(1 + m) * SLOT;
#pragma unroll
    for (int i = 0; i < 4; ++i) {
      int cb64 = (i * 8 + w) * 64;
      if (cb64 >= 1664) break;                 // wave-uniform
      int c = cb64 + lane;
      int row = c >> 3;
      int kg = (c & 7) ^ (row & 7);            // inverse swizzle on SOURCE
      async16(Kg + (rowbase + row) * KDIM + cb + kg * 8,
              (char*)KL + cb64 * 16);
    }
  };

  stageK(0);

  // stage V^T (global coalesced reads, scalar transpose writes)
  for (int e = tid; e < 64 * 228; e += 512) {
    int j = e >> 6, d = e & 63;
    u16 val = 0;
    if (j < 197) val = V[(rowbase + j) * KDIM + cb + d];
    VT[d][j] = val;
  }

  // per-lane i-side mask state
  const int i_ = rt * 16 + li;
  const int pi = i_ - 1;
  const int ri = pi / 14, ci = pi % 14;
  const bool i0 = (i_ == 0);

  // running j-side seed at (t=0, r=0): pj = g*4 - 1
  const int rs_init = (g * 4 - 1) / 14;
  const int cs_init = (g * 4 - 1) % 14;        // -1, 3, 7, 11

  // ---- keep-bits: R5's mk for all 5 masks, computed once ---------------------
  // bit(e) for element e = t*4+r == R5's: pred_m && !(i0 || jv==0).
  // No allm fallback; pads (jv>=197) irrelevant (hard-killed pre-max).
  uint32_t b0l = 0, b0h = 0, b1l = 0, b1h = 0, b2l = 0, b2h = 0,
           b3l = 0, b3h = 0, b4l = 0, b4h = 0;
  {
    int cs = cs_init, rs = rs_init;
#pragma unroll
    for (int t = 0; t < 13; ++t) {
      int jv = t * 16 + g * 4;
      int cjr = cs, rjr = rs;
#pragma unroll
      for (int r = 0; r < 4; ++r) {
        const bool ok = (jv != 0) && !i0;          // CLS row/col force-mask
        const bool k0 = (ci < cjr) && ok;          // left
        const bool k1 = (ci > cjr) && ok;          // right
        const bool k2 = (ri < rjr) && ok;          // up
        const bool k3 = (ri > rjr) && ok;          // down
        const bool k4 = (i_ == jv) && ok;          // ident
        const int e = t * 4 + r;
        const uint32_t bit = 1u << (e & 31);
        if (e < 32) {
          b0l |= k0 ? bit : 0u; b1l |= k1 ? bit : 0u; b2l |= k2 ? bit : 0u;
          b3l |= k3 ? bit : 0u; b4l |= k4 ? bit : 0u;
        } else {
          b0h |= k0 ? bit : 0u; b1h |= k1 ? bit : 0u; b2h |= k2 ? bit : 0u;
          b3h |= k3 ? bit : 0u; b4h |= k4 ? bit : 0u;
        }
        ++jv; ++cjr; if (cjr == 14) { cjr = 0; ++rjr; }
      }
      cs += 2; ++rs; if (cs >= 14) { cs -= 14; ++rs; }   // seed advance (+16)
    }
  }

  bf16x8 qa0, qa1;
  {
    const size_t qrow = rowbase + (size_t)rt * 16 + li;   // < MP rows, finite
    qa0 = *(const bf16x8*)(Q + qrow * KDIM + cb + g * 8);
    qa1 = *(const bf16x8*)(Q + qrow * KDIM + cb + 32 + g * 8);
  }

  f32x4 oacc[4] = {};

  for (int m = 0; m < nmask; ++m) {
    asm volatile("s_waitcnt vmcnt(0)" ::: "memory");  // own K loads done
    __syncthreads();                                   // all loads + VT ready

    const bool doit = task && (m < 4 || rt == 0);
    f32x4 s[13];
    if (doit) {
      // QK^T from swizzled KL, swapped operands: lane holds S^T[j][i=li]
      __builtin_amdgcn_s_setprio(1);
#pragma unroll
      for (int t = 0; t < 13; ++t) {
        const char* base = (const char*)KL + (size_t)(t * 16 + li) * 128;
        const int sw = (li & 7) << 4;
        bf16x8 kb0 = *(const bf16x8*)(base + ((g * 16) ^ sw));
        bf16x8 kb1 = *(const bf16x8*)(base + ((64 + g * 16) ^ sw));
        f32x4 zz = {};
        zz = __builtin_amdgcn_mfma_f32_16x16x32_bf16(kb0, qa0, zz, 0, 0, 0);
        zz = __builtin_amdgcn_mfma_f32_16x16x32_bf16(kb1, qa1, zz, 0, 0, 0);
        s[t] = zz;
      }
      __builtin_amdgcn_s_setprio(0);
    }
    __syncthreads();                     // all waves done reading KL
    if (m + 1 < nmask) stageK(m + 1);    // async overwrite, hidden under below

    if (doit) {
      // select this mask's bit words (wave-uniform branch)
      uint32_t wlo, whi;
      if (m == 0)      { wlo = b0l; whi = b0h; }
      else if (m == 1) { wlo = b1l; whi = b1h; }
      else if (m == 2) { wlo = b2l; whi = b2h; }
      else if (m == 3) { wlo = b3l; whi = b3h; }
      else             { wlo = b4l; whi = b4h; }

      // R5 pipeline, bit-driven: mask-add -BIGL, pad hard-kill, post-mask max
      float mx = -3.0e38f;
#pragma unroll
      for (int t = 0; t < 13; ++t) {
#pragma unroll
        for (int r = 0; r < 4; ++r) {
          const int e = t * 4 + r;
          const uint32_t w32 = (e < 32) ? wlo : whi;
          const bool mk = ((w32 >> (e & 31)) & 1u) != 0u;
          const int jv = t * 16 + g * 4 + r;
          float sv = s[t][r] - (mk ? 0.f : BIGL);
          if (jv >= 197) sv = -3.0e38f;      // pad cols: hard kill (NaN-safe)
          s[t][r] = sv;
          mx = fmaxf(mx, sv);
        }
      }
      mx = fmaxf(mx, __shfl_xor(mx, 16));
      mx = fmaxf(mx, __shfl_xor(mx, 32));
      float sum = 0.f;
#pragma unroll
      for (int t = 0; t < 13; ++t)
#pragma unroll
        for (int r = 0; r < 4; ++r) {
          float e_ = exp2f(s[t][r] - mx);
          s[t][r] = e_;
          sum += e_;
        }
      sum += __shfl_xor(sum, 16);
      sum += __shfl_xor(sum, 32);
      const float inv = 1.0f / sum;

      // PV: lag-1 pack-ahead through rotating P buffers (R5 exact)
#pragma unroll
      for (int kt = 0; kt <= 7; ++kt) {
        if (kt < 7) {
#pragma unroll
          for (int h2 = 0; h2 < 2; ++h2) {
            const int t = kt * 2 + h2;
            uint32_t w0 = 0, w1 = 0;
            if (t < 13) {
              float a0 = s[t][0] * inv, a1 = s[t][1] * inv;
              float a2 = s[t][2] * inv, a3 = s[t][3] * inv;
              asm("v_cvt_pk_bf16_f32 %0, %1, %2" : "=v"(w0) : "v"(a0), "v"(a1));
              asm("v_cvt_pk_bf16_f32 %0, %1, %2" : "=v"(w1) : "v"(a2), "v"(a3));
            }
            uint2 pw; pw.x = w0; pw.y = w1;
            *(uint2*)&P[kt & 1][w][li][h2 * 16 + g * 4] = pw;
          }
        }
        if (kt > 0) {
          const int kr = kt - 1;
          bf16x8 pa = *(const bf16x8*)&P[kr & 1][w][li][g * 8];
          __builtin_amdgcn_s_setprio(1);
#pragma unroll
          for (int dt = 0; dt < 4; ++dt) {
            bf16x8 vb = *(const bf16x8*)&VT[dt * 16 + li][kr * 32 + g * 8];
            oacc[dt] = __builtin_amdgcn_mfma_f32_16x16x32_bf16(pa, vb, oacc[dt],
                                                               0, 0, 0);
          }
          __builtin_amdgcn_s_setprio(0);
        }
      }
    }
  }

  // identity-mask contribution for non-CLS rows: P is exactly one-hot -> +V[i]
  if (task && rt > 0) {
#pragma unroll
    for (int dt = 0; dt < 4; ++dt)
#pragma unroll
      for (int r = 0; r < 4; ++r) {
        int i2 = rt * 16 + g * 4 + r;          // >=16; cols >=197 are zero
        oacc[dt][r] += b2f(VT[dt * 16 + li][i2]);
      }
  }

  if (task) {
#pragma unroll
    for (int dt = 0; dt < 4; ++dt)
#pragma unroll
      for (int r = 0; r < 4; ++r) {
        int i2 = rt * 16 + g * 4 + r;
        if (i2 < 197)
          att[(rowbase + i2) * KDIM + cb + dt * 16 + li] = f2b(oacc[dt][r]);
      }
  }
}

// -----------------------------------------------------------------------------
extern "C" void kernel_launch(void* const* d_in, const int* in_sizes, int n_in,
                              void* d_out, int out_size, void* d_ws, size_t ws_size,
                              hipStream_t stream) {
  (void)in_sizes; (void)n_in; (void)out_size; (void)ws_size;
  const float* x      = (const float*)d_in[0];
  const float* q_w    = (const float*)d_in[1];
  const float* q_b    = (const float*)d_in[2];
  const float* kA_w   = (const float*)d_in[3];
  const float* kA_b   = (const float*)d_in[4];
  const float* kB_w   = (const float*)d_in[5];
  const float* kB_b   = (const float*)d_in[6];
  const float* kC_w   = (const float*)d_in[7];
  const float* kC_b   = (const float*)d_in[8];
  const float* kD_w   = (const float*)d_in[9];
  const float* kD_b   = (const float*)d_in[10];
  const float* kE_w   = (const float*)d_in[11];
  const float* kE_b   = (const float*)d_in[12];
  const float* v_w    = (const float*)d_in[13];
  const float* v_b    = (const float*)d_in[14];
  const float* proj_w = (const float*)d_in[15];
  const float* proj_b = (const float*)d_in[16];
  float* out = (float*)d_out;

  u16* xb   = (u16*)d_ws;                 // SLOT
  u16* qkv  = xb + SLOT;                  // 7 * SLOT
  u16* wall = qkv + 7 * SLOT;             // 8 * WSZ
  u16* att  = xb;                         // reuse after gemm1 consumed x_b

  Ptr9 cs;
  cs.p[0] = x;    cs.p[1] = q_w;  cs.p[2] = kA_w; cs.p[3] = kB_w;
  cs.p[4] = kC_w; cs.p[5] = kD_w; cs.p[6] = kE_w; cs.p[7] = v_w;
  cs.p[8] = proj_w;
  k_convert<<<dim3(2048), dim3(256), 0, stream>>>(cs, xb, wall);

  Ptr7 b1;
  b1.p[0] = q_b;  b1.p[1] = kA_b; b1.p[2] = kB_b; b1.p[3] = kC_b;
  b1.p[4] = kD_b; b1.p[5] = kE_b; b1.p[6] = v_b;
  k_gemm<<<dim3(50, 6, 7), dim3(256), 0, stream>>>(xb, wall, b1, qkv, nullptr,
                                                   QSCALE_L, 0);

  k_attn<<<dim3(2, 12, 32), dim3(512), 0, stream>>>(qkv, att);

  Ptr7 b2;
  for (int i = 0; i < 7; ++i) b2.p[i] = proj_b;
  k_gemm<<<dim3(50, 6, 1), dim3(256), 0, stream>>>(att, wall + 7 * WSZ, b2,
                                                   nullptr, out, 1.0f, MREAL);
}